// Round 15
// baseline (365.903 us; speedup 1.0000x reference)
//
#include <hip/hip_runtime.h>
#include <math.h>

#define B_   16
#define TT   204800
#define FRM  800
#define FB   513
#define FBP  516   // padded row (float4-aligned) for la/kn buffers

// pad every 16 complex elements (float2) -> conflict-free strided FFT access
__device__ __forceinline__ int PD2(int i) { return i + (i >> 4); }
// 4-digit base-4 reverse (g < 256): used by the stage-0 gather
__device__ __forceinline__ int r4(int g) {
  return ((g & 3) << 6) | ((g & 12) << 2) | ((g >> 2) & 12) | ((g >> 6) & 3);
}
__device__ __forceinline__ float2 cmul(float2 a, float2 b) {
  return make_float2(a.x * b.x - a.y * b.y, a.x * b.y + a.y * b.x);
}

// ============================ twiddle table: w^k, k=0..255 (float2) ============================
__global__ void k_tw(float* tw) {
  int k = threadIdx.x;   // 256
  double a = -2.0 * 3.14159265358979323846 * (double)k / 1024.0;
  ((float2*)tw)[k] = make_float2((float)cos(a), (float)sin(a));
}

// ============================ fused f0 upsample + scan level-0 block sums ============================
// One thread = one 16-element scan block. Per-element arithmetic identical to the previous
// k_f0up (forced-unfused lerp, asm contraction barrier) -> X bit-identical; bsum0 fold identical.
__global__ __launch_bounds__(256) void k_f0b(const float* __restrict__ f0, float* __restrict__ X,
                                             float* __restrict__ Pg) {
  int i = blockIdx.x * 256 + threadIdx.x;      // 204800 blocks-of-16
  int b = i / 12800; int blk = i - b * 12800;
  int t0 = blk * 16;
  const float* fb = f0 + b * FRM;
  float xv[16];
  #pragma unroll
  for (int j = 0; j < 16; ++j) {
    int t = t0 + j;
    float p = __fsub_rn(__fadd_rn((float)t, 0.5f) / 256.0f, 0.5f);
    p = fminf(fmaxf(p, 0.0f), 799.0f);
    int i0 = (int)p;
    int i1 = i0 + 1; if (i1 > 799) i1 = 799;
    float w = __fsub_rn(p, (float)i0);
    float a = fb[i0], c = fb[i1];
    float p1 = a * (1.0f - w);
    float p2 = c * w;
    asm volatile("" : "+v"(p1), "+v"(p2));   // contraction barrier
    xv[j] = p1 + p2;
  }
  float* xo = X + (size_t)b * TT + t0;
  #pragma unroll
  for (int j = 0; j < 4; ++j)
    *(float4*)(xo + 4 * j) = make_float4(xv[4*j], xv[4*j+1], xv[4*j+2], xv[4*j+3]);
  float a = 0.0f;
  #pragma unroll
  for (int j = 0; j < 16; ++j) a = __fadd_rn(a, xv[j]);
  Pg[(size_t)b * TT + blk] = a;               // bsum0
}

// ============================ scan pyramid, upper levels (narrow, tiny) ============================
__global__ __launch_bounds__(256) void k_scan_mid(float* __restrict__ Pg) {
  const int b = blockIdx.x;
  float* P = Pg + (size_t)b * TT;
  float* bsum0 = P;            // 12800
  float* bsum1 = P + 25600;    // 800
  float* incl2 = P + 26400;    // 800
  float* bsum2 = P + 27200;    // 50
  float* incl3 = P + 27264;    // 50
  float* incl4 = P + 27328;    // 4
  const int tid = threadIdx.x;
  for (int i = tid; i < 800; i += 256) {
    float a = 0.0f;
    #pragma unroll
    for (int j = 0; j < 16; ++j) a = __fadd_rn(a, bsum0[i * 16 + j]);
    bsum1[i] = a;
  }
  __syncthreads();
  if (tid < 50) {
    float a = 0.0f;
    #pragma unroll
    for (int j = 0; j < 16; ++j) a = __fadd_rn(a, bsum1[tid * 16 + j]);
    bsum2[tid] = a;
  }
  __syncthreads();
  if (tid == 0) {
    float bs3[4];
    for (int i = 0; i < 4; ++i) {
      float a = 0.0f;
      for (int j = 0; j < 16; ++j) {
        int k = i * 16 + j;
        a = __fadd_rn(a, (k < 50) ? bsum2[k] : 0.0f);
      }
      bs3[i] = a;
    }
    float s = 0.0f;
    for (int i = 0; i < 4; ++i) { s = __fadd_rn(s, bs3[i]); incl4[i] = s; }
  }
  __syncthreads();
  if (tid < 50) {
    int blk = tid >> 4;
    float w = 0.0f;
    for (int j = blk * 16; j <= tid; ++j) w = __fadd_rn(w, bsum2[j]);
    float e = (blk == 0) ? 0.0f : incl4[blk - 1];
    incl3[tid] = __fadd_rn(e, w);
  }
  __syncthreads();
  for (int i = tid; i < 800; i += 256) {
    int blk = i >> 4;
    float w = 0.0f;
    for (int j = blk * 16; j <= i; ++j) w = __fadd_rn(w, bsum1[j]);
    float e = (blk == 0) ? 0.0f : incl3[blk - 1];
    incl2[i] = __fadd_rn(e, w);
  }
}

// ============================ scan pyramid, incl1 (wide) ============================
__global__ __launch_bounds__(256) void k_incl1(float* __restrict__ Pg) {
  int idx = blockIdx.x * 256 + threadIdx.x;     // 204800
  int b = idx / 12800; int i = idx - b * 12800;
  float* P = Pg + (size_t)b * TT;
  const float* bsum0 = P;
  const float* incl2 = P + 26400;
  int blk = i >> 4;
  float w = 0.0f;
  for (int j = blk * 16; j <= i; ++j) w = __fadd_rn(w, bsum0[j]);
  float e = (blk == 0) ? 0.0f : incl2[blk - 1];
  P[12800 + i] = __fadd_rn(e, w);               // incl1
}

// ============================ fused scan-final + impulse extraction ============================
__global__ __launch_bounds__(256) void k_scan_imp(const float* __restrict__ Xg, const float* __restrict__ Pg,
                                                  float* __restrict__ imp) {
  int idx = blockIdx.x * 256 + threadIdx.x;
  int b = idx / TT; int t = idx - b * TT;
  const float* x = Xg + (size_t)b * TT;
  const float* incl1 = Pg + (size_t)b * TT + 12800;
  int blk = t >> 4;
  float e = (blk == 0) ? 0.0f : incl1[blk - 1];
  float w = 0.0f;
  for (int j = blk * 16; j <= t; ++j) w = __fadd_rn(w, x[j]);
  float St = __fadd_rn(e, w);
  float st = St / 24000.0f;
  bool cross;
  if (t < TT - 1) {
    float St1 = ((t & 15) == 15) ? __fadd_rn(incl1[blk], x[t + 1])
                                 : __fadd_rn(e, __fadd_rn(w, x[t + 1]));
    cross = floorf(St1 / 24000.0f) > floorf(st);
  } else {
    float s0 = x[0] / 24000.0f;              // S[0] = RN(0 + x[0]) = x[0]
    float sawt = __fsub_rn(st, floorf(st));
    float saw0 = __fsub_rn(s0, floorf(s0));
    cross = __fsub_rn(sawt, saw0) > 0.5f;
  }
  float v = 0.0f;
  if (cross) {
    float m = fmaxf(Xg[idx], 20.0f);
    v = 154.9193338f * (1.0f / sqrtf(m));
  }
  imp[idx] = v;
}

// ============================ 256-tap vocal-cord FIR (sliding window, 4 outs/thread) ============================
__global__ __launch_bounds__(256) void k_conv(const float* __restrict__ imp, const float* __restrict__ vc,
                                              float* __restrict__ outc) {
  int gid = blockIdx.x; int b = gid / 200; int tile = gid % 200; int t0 = tile * 1024;
  __shared__ float sx[1280 + 80];   // padded: index i stored at i + (i>>4)
  __shared__ float sv[256];
  int tid = threadIdx.x;
  sv[tid] = vc[b * 256 + tid];
  for (int idx = tid; idx < 1280; idx += 256) {
    int g = t0 - 256 + idx;
    sx[idx + (idx >> 4)] = (g >= 0) ? imp[(size_t)b * TT + g] : 0.0f;
  }
  __syncthreads();
  #define SXX(i) sx[(i) + ((i) >> 4)]
  int tl = tid * 4;
  int base = 256 + tl;
  float w0 = SXX(base), w1 = SXX(base + 1), w2 = SXX(base + 2), w3 = SXX(base + 3);
  float a0 = 0.0f, a1 = 0.0f, a2 = 0.0f, a3 = 0.0f;
  #pragma unroll 8
  for (int j = 0; j < 256; ++j) {
    float h = sv[j];
    a0 += h * w0; a1 += h * w1; a2 += h * w2; a3 += h * w3;
    w3 = w2; w2 = w1; w1 = w0;
    w0 = SXX(base - 1 - j);
  }
  *(float4*)(outc + (size_t)b * TT + t0 + tl) = make_float4(a0, a1, a2, a3);
  #undef SXX
}

// ============================ envelope einsums: A-tile in LDS, B direct from global ============================
// la[b][f][k] = log(max(invmel[k,:]·envi[b,:,f],1e-6)); kn = relu(invmel·envn).
// B reads are float4, coalesced across tx (256B/row), L2-resident. LDS = 21.8 KB -> ~5 blocks/CU.
__global__ __launch_bounds__(256) void k_dots(const float* __restrict__ invmel,
                                              const float* __restrict__ envi,
                                              const float* __restrict__ envn,
                                              float* __restrict__ la, float* __restrict__ kn) {
  const int NKT = 9, NFT = 13;
  int bid = blockIdx.x;
  int b = bid / (NKT * NFT);
  int r = bid % (NKT * NFT);
  int kt = r / NFT, ft = r % NFT;
  int k0 = kt * 64, f0 = ft * 64;
  __shared__ float at[80][68];
  int tid = threadIdx.x;
  {
    int kk = tid >> 2, mb = (tid & 3) * 20;
    int kg = k0 + kk;
    const float* src = invmel + kg * 80 + mb;
    #pragma unroll 5
    for (int q = 0; q < 20; ++q) at[mb + q][kk] = (kg < 513) ? src[q] : 0.0f;
  }
  __syncthreads();
  int tx = tid & 15, ty = tid >> 4;
  int fg0 = f0 + tx * 4;                        // all 4 cols in/out of range together (800 % 4 == 0)
  bool fok = fg0 < FRM;
  float ai[4][4], an[4][4];
  #pragma unroll
  for (int u = 0; u < 4; ++u)
    #pragma unroll
    for (int v = 0; v < 4; ++v) { ai[u][v] = 0.0f; an[u][v] = 0.0f; }
  if (fok) {
    const float* pi = envi + (size_t)b * 80 * FRM + fg0;
    const float* pn = envn + (size_t)b * 80 * FRM + fg0;
    #pragma unroll 4
    for (int m = 0; m < 80; ++m) {
      float4 a4 = *(const float4*)&at[m][ty * 4];
      float4 i4 = *(const float4*)(pi + (size_t)m * FRM);
      float4 n4 = *(const float4*)(pn + (size_t)m * FRM);
      float ar[4] = {a4.x, a4.y, a4.z, a4.w};
      float ir[4] = {i4.x, i4.y, i4.z, i4.w};
      float nr[4] = {n4.x, n4.y, n4.z, n4.w};
      #pragma unroll
      for (int u = 0; u < 4; ++u)
        #pragma unroll
        for (int v = 0; v < 4; ++v) { ai[u][v] += ar[u] * ir[v]; an[u][v] += ar[u] * nr[v]; }
    }
  }
  int kg = k0 + ty * 4;
  if (kg <= 512 && fok) {
    #pragma unroll
    for (int v = 0; v < 4; ++v) {
      int fg = fg0 + v;
      float4 vl, vk;
      vl.x = __logf(fmaxf(ai[0][v], 1e-6f)); vl.y = __logf(fmaxf(ai[1][v], 1e-6f));
      vl.z = __logf(fmaxf(ai[2][v], 1e-6f)); vl.w = __logf(fmaxf(ai[3][v], 1e-6f));
      vk.x = fmaxf(an[0][v], 0.0f); vk.y = fmaxf(an[1][v], 0.0f);
      vk.z = fmaxf(an[2][v], 0.0f); vk.w = fmaxf(an[3][v], 0.0f);
      *(float4*)(la + ((size_t)b * FRM + fg) * FBP + kg) = vl;
      *(float4*)(kn + ((size_t)b * FRM + fg) * FBP + kg) = vk;
    }
  }
}

// ============================ in-LDS radix-4 1024-pt FFT, NATURAL in / NATURAL out ============================
__device__ __forceinline__ void fftc(float2* c, const float2* tw, bool inv) {
  int tid = threadIdx.x;  // 256 threads
  __syncthreads();
  {
    int rb = r4(tid);
    float2 a0 = c[PD2(rb)], a1 = c[PD2(rb + 256)], a2 = c[PD2(rb + 512)], a3 = c[PD2(rb + 768)];
    __syncthreads();
    float t0r = a0.x + a2.x, t0i = a0.y + a2.y;
    float t1r = a0.x - a2.x, t1i = a0.y - a2.y;
    float t2r = a1.x + a3.x, t2i = a1.y + a3.y;
    float t3r = a1.x - a3.x, t3i = a1.y - a3.y;
    int base = tid << 2;
    c[PD2(base)]     = make_float2(t0r + t2r, t0i + t2i);
    c[PD2(base + 2)] = make_float2(t0r - t2r, t0i - t2i);
    if (!inv) {
      c[PD2(base + 1)] = make_float2(t1r + t3i, t1i - t3r);
      c[PD2(base + 3)] = make_float2(t1r - t3i, t1i + t3r);
    } else {
      c[PD2(base + 1)] = make_float2(t1r - t3i, t1i + t3r);
      c[PD2(base + 3)] = make_float2(t1r + t3i, t1i - t3r);
    }
    __syncthreads();
  }
  #pragma unroll
  for (int s = 1; s < 5; ++s) {
    int m = 1 << (2 * s);
    int pos = tid & (m - 1);
    int grp = tid >> (2 * s);
    int base = grp * (m << 2) + pos;
    int i0 = PD2(base), i1 = PD2(base + m), i2 = PD2(base + 2 * m), i3 = PD2(base + 3 * m);
    float2 a0 = c[i0], a1 = c[i1], a2 = c[i2], a3 = c[i3];
    {
      int r = 256 >> (2 * s);
      float2 w1 = tw[PD2(pos * r)];
      if (inv) w1.y = -w1.y;
      float2 w2 = cmul(w1, w1);
      float2 w3 = cmul(w2, w1);
      a1 = cmul(a1, w1); a2 = cmul(a2, w2); a3 = cmul(a3, w3);
    }
    float t0r = a0.x + a2.x, t0i = a0.y + a2.y;
    float t1r = a0.x - a2.x, t1i = a0.y - a2.y;
    float t2r = a1.x + a3.x, t2i = a1.y + a3.y;
    float t3r = a1.x - a3.x, t3i = a1.y - a3.y;
    c[i0] = make_float2(t0r + t2r, t0i + t2i);
    c[i2] = make_float2(t0r - t2r, t0i - t2i);
    if (!inv) {
      c[i1] = make_float2(t1r + t3i, t1i - t3r);
      c[i3] = make_float2(t1r - t3i, t1i + t3r);
    } else {
      c[i1] = make_float2(t1r - t3i, t1i + t3r);
      c[i3] = make_float2(t1r + t3i, t1i - t3r);
    }
    __syncthreads();
  }
}

#define LOAD_TWL() do { twl[PD2(tid)] = ((const float2*)twg)[tid]; } while (0)

// ============================ minimum phase (2 frames per WG, packed) ============================
__global__ __launch_bounds__(256) void k_minphase(const float* __restrict__ envimp, const float* __restrict__ invmel,
                                                  float* __restrict__ kimp, const float* __restrict__ twg,
                                                  const float* __restrict__ lab) {
  int gid = blockIdx.x; int b = gid / 400; int t0 = (gid % 400) * 2;
  __shared__ float2 c[1088], twl[272];
  __shared__ float envc[160];
  int tid = threadIdx.x;
  LOAD_TWL();
  if (!lab && tid < 160) {
    int mm = tid >> 1, fr2 = tid & 1;
    envc[tid] = envimp[((size_t)b * 80 + mm) * FRM + t0 + fr2];
  }
  __syncthreads();
  if (lab) {
    const float* l1 = lab + ((size_t)b * FRM + t0) * FBP;
    const float* l2 = lab + ((size_t)b * FRM + t0 + 1) * FBP;
    for (int f = tid; f < 513; f += 256) {
      float la1 = l1[f], la2 = l2[f];
      c[PD2(f)] = make_float2(la1, la2);
      if (f >= 1 && f <= 511) c[PD2(1024 - f)] = make_float2(la1, la2);
    }
  } else {
    for (int f = tid; f < 513; f += 256) {
      const float4* iv = (const float4*)(invmel + f * 80);
      float d1 = 0.0f, d2 = 0.0f;
      #pragma unroll 5
      for (int q = 0; q < 20; ++q) {
        float4 v = iv[q];
        d1 += v.x * envc[8*q]   + v.y * envc[8*q+2] + v.z * envc[8*q+4] + v.w * envc[8*q+6];
        d2 += v.x * envc[8*q+1] + v.y * envc[8*q+3] + v.z * envc[8*q+5] + v.w * envc[8*q+7];
      }
      float la1 = __logf(fmaxf(d1, 1e-6f));
      float la2 = __logf(fmaxf(d2, 1e-6f));
      c[PD2(f)] = make_float2(la1, la2);
      if (f >= 1 && f <= 511) c[PD2(1024 - f)] = make_float2(la1, la2);
    }
  }
  fftc(c, twl, true);
  for (int n = tid; n < 1024; n += 256) {
    float sn = ((n == 0 || n == 512) ? 1.0f : (n < 512 ? 2.0f : 0.0f)) * (1.0f / 1024.0f);
    int pn = PD2(n);
    c[pn].x *= sn; c[pn].y *= sn;
  }
  fftc(c, twl, false);
  for (int k = tid; k <= 512; k += 256) {
    int km = (1024 - k) & 1023;
    float2 z = c[PD2(k)], mm2 = c[PD2(km)];
    float f1r = 0.5f * (z.x + mm2.x), f1i = 0.5f * (z.y - mm2.y);
    float f2r = 0.5f * (z.y + mm2.y), f2i = 0.5f * (mm2.x - z.x);
    float e1 = __expf(f1r), e2 = __expf(f2r);
    float s1, c1, s2, c2;
    __sincosf(f1i, &s1, &c1);
    __sincosf(f2i, &s2, &c2);
    float2* o1 = (float2*)kimp + (size_t)(b * FRM + t0) * FB + k;
    float2* o2 = (float2*)kimp + (size_t)(b * FRM + t0 + 1) * FB + k;
    *o1 = make_float2(e1 * c1, e1 * s1);
    *o2 = make_float2(e2 * c2, e2 * s2);
  }
}

// ============================ STFT -> filter -> paired iSTFT (2 frames per WG) ============================
__global__ __launch_bounds__(256) void k_combine2(const float* __restrict__ impc, const float* __restrict__ noise,
                                                  const float* __restrict__ hann, const float* __restrict__ kimp,
                                                  const float* __restrict__ invmel, const float* __restrict__ envnoi,
                                                  float* __restrict__ frames, const float* __restrict__ twg,
                                                  const float* __restrict__ knb) {
  int gid = blockIdx.x; int b = gid / 400; int pr = gid % 400;
  int fA = 2 * pr + 1, fB = fA + 1;           // frames 1..800, paired
  __shared__ float2 c[1088], twl[272], vvA[545], vvB[545];
  __shared__ float envA[80], envB[80];
  int tid = threadIdx.x;
  LOAD_TWL();
  if (!knb && tid < 160) {
    int mm = tid >> 1;
    if (tid & 1) envB[mm] = envnoi[((size_t)b * 80 + mm) * FRM + (fB - 1)];
    else         envA[mm] = envnoi[((size_t)b * 80 + mm) * FRM + (fA - 1)];
  }
  #pragma unroll
  for (int pass = 0; pass < 2; ++pass) {
    int f = pass ? fB : fA;
    for (int n = tid; n < 1024; n += 256) {
      int ip = f * 256 + n - 512;
      int ridx = ip < 0 ? -ip : (ip >= TT ? 2 * TT - 2 - ip : ip);   // reflect pad
      float wv = hann[n];
      c[PD2(n)] = make_float2(impc[(size_t)b * TT + ridx] * wv,
                              noise[(size_t)b * TT + ridx] * 0.33333f * wv);
    }
    fftc(c, twl, false);
    const float* knrow = knb ? (knb + ((size_t)b * FRM + (f - 1)) * FBP) : nullptr;
    const float* env = pass ? envB : envA;
    float2* vv = pass ? vvB : vvA;
    for (int k = tid; k <= 512; k += 256) {
      int km = (1024 - k) & 1023;
      float2 z = c[PD2(k)], mm2 = c[PD2(km)];
      float Ir = 0.5f * (z.x + mm2.x), Ii = 0.5f * (z.y - mm2.y);
      float Nr = 0.5f * (z.y + mm2.y), Ni = 0.5f * (mm2.x - z.x);
      float2 kp = ((const float2*)kimp)[(size_t)(b * FRM + f - 1) * FB + k];
      float kn;
      if (knrow) {
        kn = knrow[k];
      } else {
        const float4* iv = (const float4*)(invmel + k * 80);
        float dot = 0.0f;
        #pragma unroll 5
        for (int q = 0; q < 20; ++q) {
          float4 v = iv[q];
          dot += v.x * env[4*q] + v.y * env[4*q+1] + v.z * env[4*q+2] + v.w * env[4*q+3];
        }
        kn = dot > 0.0f ? dot : 0.0f;
      }
      vv[PD2(k)] = make_float2(Ir * kp.x - Ii * kp.y + Nr * kn,
                               Ir * kp.y + Ii * kp.x + Ni * kn);
    }
    __syncthreads();   // vv complete; safe to overwrite c next pass
  }
  // paired inverse: IFFT(V_A + i*V_B) = frame_A + i*frame_B
  for (int n = tid; n < 1024; n += 256) {
    float2 v;
    if (n <= 512) {
      float2 a = vvA[PD2(n)], bb = vvB[PD2(n)];
      v = make_float2(a.x - bb.y, a.y + bb.x);
    } else {
      float2 a = vvA[PD2(1024 - n)], bb = vvB[PD2(1024 - n)];   // conj(a) + i*conj(b)
      v = make_float2(a.x + bb.y, bb.x - a.y);
    }
    c[PD2(n)] = v;
  }
  fftc(c, twl, true);
  float* frA = frames + ((size_t)b * FRM + fA - 1) * 1024;
  float* frB = frames + ((size_t)b * FRM + fB - 1) * 1024;
  for (int n = tid; n < 1024; n += 256) {
    float2 y = c[PD2(n)];
    float hw = (1.0f / 1024.0f) * hann[n];
    frA[n] = y.x * hw;
    frB[n] = y.y * hw;
  }
}

// ============================ overlap-add + window-square normalize + crop ============================
__global__ __launch_bounds__(256) void k_ola(const float* __restrict__ frames, const float* __restrict__ hann,
                                             float* __restrict__ voi) {
  int idx = blockIdx.x * 256 + threadIdx.x;
  int b = idx / TT; int t2 = idx - b * TT;
  int i = t2 + 512;
  int fhi = i >> 8;
  float sum = 0.0f, wsq = 0.0f;
  for (int f = fhi - 3; f <= fhi; ++f) {
    if (f < 0 || f > 800) continue;
    int n = i - (f << 8);
    float wv = hann[n];
    wsq += wv * wv;
    if (f >= 1) sum += frames[((size_t)b * FRM + f - 1) * 1024 + n];
  }
  voi[idx] = sum / (wsq > 1e-11f ? wsq : 1.0f);
}

// ============================ reverb: partition FFTs ============================
__global__ __launch_bounds__(256) void k_hspec(const float* __restrict__ rvb, float* __restrict__ hs,
                                               const float* __restrict__ twg) {
  int gid = blockIdx.x; int b = gid / 16; int p = gid % 16;
  __shared__ float2 c[1088], twl[272];
  int tid = threadIdx.x;
  LOAD_TWL();
  for (int n = tid; n < 1024; n += 256) {
    c[PD2(n)] = make_float2((n < 512) ? rvb[(size_t)b * 8192 + p * 512 + n] : 0.0f, 0.0f);
  }
  fftc(c, twl, false);
  for (int k = tid; k <= 512; k += 256) {
    ((float2*)hs)[(size_t)(b * 16 + p) * FB + k] = c[PD2(k)];
  }
}

// ============================ voi spectra: 2 segments per FFT (real pairing) ============================
__global__ __launch_bounds__(256) void k_xspec2(const float* __restrict__ voi, float* __restrict__ xs,
                                                const float* __restrict__ twg) {
  int gid = blockIdx.x; int b = gid / 200; int mA = 2 * (gid % 200);   // segments mA, mA+1
  __shared__ float2 c[1088], twl[272];
  int tid = threadIdx.x;
  LOAD_TWL();
  const float* vb = voi + (size_t)b * TT;
  for (int n = tid; n < 1024; n += 256) {
    int gA = (mA - 1) * 512 + n;        // segment mA input
    int gB = gA + 512;                  // segment mA+1 input
    float xa = (gA >= 0) ? vb[gA] : 0.0f;
    float xb = vb[gB];                  // gB >= 0 always (mA >= 0)
    c[PD2(n)] = make_float2(xa, xb);
  }
  fftc(c, twl, false);
  float2* xsA = (float2*)xs + (size_t)(b * 400 + mA) * FB;
  float2* xsB = (float2*)xs + (size_t)(b * 400 + mA + 1) * FB;
  for (int k = tid; k <= 512; k += 256) {
    int km = (1024 - k) & 1023;
    float2 z = c[PD2(k)], w = c[PD2(km)];
    xsA[k] = make_float2(0.5f * (z.x + w.x), 0.5f * (z.y - w.y));
    xsB[k] = make_float2(0.5f * (z.y + w.y), 0.5f * (w.x - z.x));
  }
}

// ============================ reverb: accumulate + paired inverse (2 segments per WG) ============================
__global__ __launch_bounds__(256) void k_r22(const float* __restrict__ xsp, const float* __restrict__ hsp,
                                             float* __restrict__ out, const float* __restrict__ twg) {
  int gid = blockIdx.x; int b = gid / 200; int mA = 2 * (gid % 200); int mB = mA + 1;
  __shared__ float2 c[1088], twl[272], vvA[545], vvB[545];
  int tid = threadIdx.x;
  LOAD_TWL();
  const float2* X = (const float2*)xsp + (size_t)b * 400 * FB;
  const float2* H = (const float2*)hsp + (size_t)b * 16 * FB;
  for (int k = tid; k <= 512; k += 256) {
    float arA = 0.0f, aiA = 0.0f, arB = 0.0f, aiB = 0.0f;
    #pragma unroll 4
    for (int jj = 0; jj <= 16; ++jj) {      // j = mB - jj; shares X loads between segments
      int j = mB - jj;
      if (j < 0) break;
      float2 xj = X[(size_t)j * FB + k];
      if (jj <= 15) {
        float2 h = H[(size_t)jj * FB + k];
        arB += xj.x * h.x - xj.y * h.y;
        aiB += xj.x * h.y + xj.y * h.x;
      }
      if (jj >= 1) {
        float2 h = H[(size_t)(jj - 1) * FB + k];
        arA += xj.x * h.x - xj.y * h.y;
        aiA += xj.x * h.y + xj.y * h.x;
      }
    }
    vvA[PD2(k)] = make_float2(arA, aiA);
    vvB[PD2(k)] = make_float2(arB, aiB);
  }
  __syncthreads();
  for (int n = tid; n < 1024; n += 256) {
    float2 v;
    if (n <= 512) {
      float2 a = vvA[PD2(n)], bb = vvB[PD2(n)];
      v = make_float2(a.x - bb.y, a.y + bb.x);
    } else {
      float2 a = vvA[PD2(1024 - n)], bb = vvB[PD2(1024 - n)];
      v = make_float2(a.x + bb.y, bb.x - a.y);
    }
    c[PD2(n)] = v;
  }
  fftc(c, twl, true);
  float* oA = out + (size_t)b * TT + mA * 512;
  float* oB = out + (size_t)b * TT + mB * 512;
  for (int n2 = tid; n2 < 512; n2 += 256) {
    float2 y = c[PD2(512 + n2)];
    oA[n2] = y.x * (1.0f / 1024.0f);
    oB[n2] = y.y * (1.0f / 1024.0f);
  }
}

// ============================ launch ============================
extern "C" void kernel_launch(void* const* d_in, const int* in_sizes, int n_in,
                              void* d_out, int out_size, void* d_ws, size_t ws_size,
                              hipStream_t stream) {
  const float* f0   = (const float*)d_in[0];
  const float* envi = (const float*)d_in[1];
  const float* envn = (const float*)d_in[2];
  const float* vc   = (const float*)d_in[3];
  const float* rvb  = (const float*)d_in[4];
  const float* noi  = (const float*)d_in[5];
  const float* hann = (const float*)d_in[6];
  const float* iml  = (const float*)d_in[7];
  float* out = (float*)d_out;
  float* ws  = (float*)d_ws;

  size_t o = 0;
  float* bufX = ws + o; o += (size_t)B_ * TT;              // f0_up -> imp_c
  float* bufS = ws + o; o += (size_t)B_ * TT;              // imp -> voi
  float* bufK = ws + o; o += (size_t)B_ * FRM * FB * 2;    // kimp -> H spectra
  float* bufF = ws + o; o += (size_t)B_ * FRM * 1024;      // la overlay -> frames -> X spectra
  float* bufT = ws + o; o += 600;                          // twiddles (256 float2)
  float* bufKN = ws + o; o += (size_t)B_ * FRM * FBP;      // kernel_noi (guarded)
  bool pre = (o * sizeof(float) <= ws_size);
  float* la = pre ? bufF : nullptr;                        // la overlays bufF (dead until combine)
  float* kn = pre ? bufKN : nullptr;

  hipLaunchKernelGGL(k_tw,       dim3(1),     dim3(256),  0, stream, bufT);
  hipLaunchKernelGGL(k_f0b,      dim3(800),   dim3(256),  0, stream, f0, bufX, out);    // X + bsum0 (out = pyramid)
  hipLaunchKernelGGL(k_scan_mid, dim3(16),    dim3(256),  0, stream, out);
  hipLaunchKernelGGL(k_incl1,    dim3(800),   dim3(256),  0, stream, out);
  hipLaunchKernelGGL(k_scan_imp, dim3(12800), dim3(256),  0, stream, bufX, out, bufS);  // imp -> bufS
  hipLaunchKernelGGL(k_conv,     dim3(3200),  dim3(256),  0, stream, bufS, vc, bufX);   // imp_c -> bufX
  if (pre)
    hipLaunchKernelGGL(k_dots,   dim3(16 * 9 * 13), dim3(256), 0, stream, iml, envi, envn, la, kn);
  hipLaunchKernelGGL(k_minphase, dim3(6400),  dim3(256),  0, stream, envi, iml, bufK, bufT, la);
  hipLaunchKernelGGL(k_combine2, dim3(6400),  dim3(256),  0, stream, bufX, noi, hann, bufK, iml, envn, bufF, bufT, kn);
  hipLaunchKernelGGL(k_ola,      dim3(12800), dim3(256),  0, stream, bufF, hann, bufS);
  hipLaunchKernelGGL(k_hspec,    dim3(256),   dim3(256),  0, stream, rvb, bufK, bufT);
  hipLaunchKernelGGL(k_xspec2,   dim3(3200),  dim3(256),  0, stream, bufS, bufF, bufT);
  hipLaunchKernelGGL(k_r22,      dim3(3200),  dim3(256),  0, stream, bufF, bufK, out, bufT);
}

// Round 16
// 362.931 us; speedup vs baseline: 1.0082x; 1.0082x over previous
//
#include <hip/hip_runtime.h>
#include <math.h>

#define B_   16
#define TT   204800
#define FRM  800
#define FB   513
#define FBP  516   // padded row (float4-aligned) for la/kn buffers

// pad every 16 complex elements (float2) -> conflict-free strided FFT access
__device__ __forceinline__ int PD2(int i) { return i + (i >> 4); }
// 4-digit base-4 reverse (g < 256): used by the stage-0 gather
__device__ __forceinline__ int r4(int g) {
  return ((g & 3) << 6) | ((g & 12) << 2) | ((g >> 2) & 12) | ((g >> 6) & 3);
}
__device__ __forceinline__ float2 cmul(float2 a, float2 b) {
  return make_float2(a.x * b.x - a.y * b.y, a.x * b.y + a.y * b.x);
}

// ============================ twiddle table: w^k, k=0..255 (float2) ============================
__global__ void k_tw(float* tw) {
  int k = threadIdx.x;   // 256
  double a = -2.0 * 3.14159265358979323846 * (double)k / 1024.0;
  ((float2*)tw)[k] = make_float2((float)cos(a), (float)sin(a));
}

// ============================ fused f0 upsample + scan level-0 block sums ============================
__global__ __launch_bounds__(256) void k_f0b(const float* __restrict__ f0, float* __restrict__ X,
                                             float* __restrict__ Pg) {
  int i = blockIdx.x * 256 + threadIdx.x;      // 204800 blocks-of-16
  int b = i / 12800; int blk = i - b * 12800;
  int t0 = blk * 16;
  const float* fb = f0 + b * FRM;
  float xv[16];
  #pragma unroll
  for (int j = 0; j < 16; ++j) {
    int t = t0 + j;
    float p = __fsub_rn(__fadd_rn((float)t, 0.5f) / 256.0f, 0.5f);
    p = fminf(fmaxf(p, 0.0f), 799.0f);
    int i0 = (int)p;
    int i1 = i0 + 1; if (i1 > 799) i1 = 799;
    float w = __fsub_rn(p, (float)i0);
    float a = fb[i0], c = fb[i1];
    float p1 = a * (1.0f - w);
    float p2 = c * w;
    asm volatile("" : "+v"(p1), "+v"(p2));   // contraction barrier
    xv[j] = p1 + p2;
  }
  float* xo = X + (size_t)b * TT + t0;
  #pragma unroll
  for (int j = 0; j < 4; ++j)
    *(float4*)(xo + 4 * j) = make_float4(xv[4*j], xv[4*j+1], xv[4*j+2], xv[4*j+3]);
  float a = 0.0f;
  #pragma unroll
  for (int j = 0; j < 16; ++j) a = __fadd_rn(a, xv[j]);
  Pg[(size_t)b * TT + blk] = a;               // bsum0
}

// ============================ scan pyramid, upper levels (narrow, tiny) ============================
__global__ __launch_bounds__(256) void k_scan_mid(float* __restrict__ Pg) {
  const int b = blockIdx.x;
  float* P = Pg + (size_t)b * TT;
  float* bsum0 = P;            // 12800
  float* bsum1 = P + 25600;    // 800
  float* incl2 = P + 26400;    // 800
  float* bsum2 = P + 27200;    // 50
  float* incl3 = P + 27264;    // 50
  float* incl4 = P + 27328;    // 4
  const int tid = threadIdx.x;
  for (int i = tid; i < 800; i += 256) {
    float a = 0.0f;
    #pragma unroll
    for (int j = 0; j < 16; ++j) a = __fadd_rn(a, bsum0[i * 16 + j]);
    bsum1[i] = a;
  }
  __syncthreads();
  if (tid < 50) {
    float a = 0.0f;
    #pragma unroll
    for (int j = 0; j < 16; ++j) a = __fadd_rn(a, bsum1[tid * 16 + j]);
    bsum2[tid] = a;
  }
  __syncthreads();
  if (tid == 0) {
    float bs3[4];
    for (int i = 0; i < 4; ++i) {
      float a = 0.0f;
      for (int j = 0; j < 16; ++j) {
        int k = i * 16 + j;
        a = __fadd_rn(a, (k < 50) ? bsum2[k] : 0.0f);
      }
      bs3[i] = a;
    }
    float s = 0.0f;
    for (int i = 0; i < 4; ++i) { s = __fadd_rn(s, bs3[i]); incl4[i] = s; }
  }
  __syncthreads();
  if (tid < 50) {
    int blk = tid >> 4;
    float w = 0.0f;
    for (int j = blk * 16; j <= tid; ++j) w = __fadd_rn(w, bsum2[j]);
    float e = (blk == 0) ? 0.0f : incl4[blk - 1];
    incl3[tid] = __fadd_rn(e, w);
  }
  __syncthreads();
  for (int i = tid; i < 800; i += 256) {
    int blk = i >> 4;
    float w = 0.0f;
    for (int j = blk * 16; j <= i; ++j) w = __fadd_rn(w, bsum1[j]);
    float e = (blk == 0) ? 0.0f : incl3[blk - 1];
    incl2[i] = __fadd_rn(e, w);
  }
}

// ============================ scan pyramid, incl1 (wide) ============================
__global__ __launch_bounds__(256) void k_incl1(float* __restrict__ Pg) {
  int idx = blockIdx.x * 256 + threadIdx.x;     // 204800
  int b = idx / 12800; int i = idx - b * 12800;
  float* P = Pg + (size_t)b * TT;
  const float* bsum0 = P;
  const float* incl2 = P + 26400;
  int blk = i >> 4;
  float w = 0.0f;
  for (int j = blk * 16; j <= i; ++j) w = __fadd_rn(w, bsum0[j]);
  float e = (blk == 0) ? 0.0f : incl2[blk - 1];
  P[12800 + i] = __fadd_rn(e, w);               // incl1
}

// ============================ fused scan-final + impulse extraction ============================
__global__ __launch_bounds__(256) void k_scan_imp(const float* __restrict__ Xg, const float* __restrict__ Pg,
                                                  float* __restrict__ imp) {
  int idx = blockIdx.x * 256 + threadIdx.x;
  int b = idx / TT; int t = idx - b * TT;
  const float* x = Xg + (size_t)b * TT;
  const float* incl1 = Pg + (size_t)b * TT + 12800;
  int blk = t >> 4;
  float e = (blk == 0) ? 0.0f : incl1[blk - 1];
  float w = 0.0f;
  for (int j = blk * 16; j <= t; ++j) w = __fadd_rn(w, x[j]);
  float St = __fadd_rn(e, w);
  float st = St / 24000.0f;
  bool cross;
  if (t < TT - 1) {
    float St1 = ((t & 15) == 15) ? __fadd_rn(incl1[blk], x[t + 1])
                                 : __fadd_rn(e, __fadd_rn(w, x[t + 1]));
    cross = floorf(St1 / 24000.0f) > floorf(st);
  } else {
    float s0 = x[0] / 24000.0f;              // S[0] = RN(0 + x[0]) = x[0]
    float sawt = __fsub_rn(st, floorf(st));
    float saw0 = __fsub_rn(s0, floorf(s0));
    cross = __fsub_rn(sawt, saw0) > 0.5f;
  }
  float v = 0.0f;
  if (cross) {
    float m = fmaxf(Xg[idx], 20.0f);
    v = 154.9193338f * (1.0f / sqrtf(m));
  }
  imp[idx] = v;
}

// ============================ 256-tap vocal-cord FIR (sliding window, 4 outs/thread) ============================
__global__ __launch_bounds__(256) void k_conv(const float* __restrict__ imp, const float* __restrict__ vc,
                                              float* __restrict__ outc) {
  int gid = blockIdx.x; int b = gid / 200; int tile = gid % 200; int t0 = tile * 1024;
  __shared__ float sx[1280 + 80];   // padded: index i stored at i + (i>>4)
  __shared__ float sv[256];
  int tid = threadIdx.x;
  sv[tid] = vc[b * 256 + tid];
  for (int idx = tid; idx < 1280; idx += 256) {
    int g = t0 - 256 + idx;
    sx[idx + (idx >> 4)] = (g >= 0) ? imp[(size_t)b * TT + g] : 0.0f;
  }
  __syncthreads();
  #define SXX(i) sx[(i) + ((i) >> 4)]
  int tl = tid * 4;
  int base = 256 + tl;
  float w0 = SXX(base), w1 = SXX(base + 1), w2 = SXX(base + 2), w3 = SXX(base + 3);
  float a0 = 0.0f, a1 = 0.0f, a2 = 0.0f, a3 = 0.0f;
  #pragma unroll 8
  for (int j = 0; j < 256; ++j) {
    float h = sv[j];
    a0 += h * w0; a1 += h * w1; a2 += h * w2; a3 += h * w3;
    w3 = w2; w2 = w1; w1 = w0;
    w0 = SXX(base - 1 - j);
  }
  *(float4*)(outc + (size_t)b * TT + t0 + tl) = make_float4(a0, a1, a2, a3);
  #undef SXX
}

// ============================ envelope einsums as tiled GEMM (round-14 LDS version) ============================
__global__ __launch_bounds__(256) void k_dots(const float* __restrict__ invmel,
                                              const float* __restrict__ envi,
                                              const float* __restrict__ envn,
                                              float* __restrict__ la, float* __restrict__ kn) {
  const int NKT = 9, NFT = 13;
  int bid = blockIdx.x;
  int b = bid / (NKT * NFT);
  int r = bid % (NKT * NFT);
  int kt = r / NFT, ft = r % NFT;
  int k0 = kt * 64, f0 = ft * 64;
  __shared__ float at[80][68], bi[80][68], bn[80][68];
  int tid = threadIdx.x;
  {
    int kk = tid >> 2, mb = (tid & 3) * 20;
    int kg = k0 + kk;
    const float* src = invmel + kg * 80 + mb;
    #pragma unroll 5
    for (int q = 0; q < 20; ++q) at[mb + q][kk] = (kg < 513) ? src[q] : 0.0f;
  }
  {
    int m0 = tid >> 4;
    int fc = (tid & 15) * 4;
    for (int mm = m0; mm < 80; mm += 16) {
      const float* pi = envi + ((size_t)b * 80 + mm) * FRM + f0 + fc;
      const float* pn = envn + ((size_t)b * 80 + mm) * FRM + f0 + fc;
      #pragma unroll
      for (int q = 0; q < 4; ++q) {
        int fg = f0 + fc + q;
        float vi = 0.0f, vn = 0.0f;
        if (fg < FRM) { vi = pi[q]; vn = pn[q]; }
        bi[mm][fc + q] = vi;
        bn[mm][fc + q] = vn;
      }
    }
  }
  __syncthreads();
  int tx = tid & 15, ty = tid >> 4;
  float ai[4][4], an[4][4];
  #pragma unroll
  for (int u = 0; u < 4; ++u)
    #pragma unroll
    for (int v = 0; v < 4; ++v) { ai[u][v] = 0.0f; an[u][v] = 0.0f; }
  #pragma unroll 8
  for (int m = 0; m < 80; ++m) {
    float4 a4 = *(const float4*)&at[m][ty * 4];
    float4 i4 = *(const float4*)&bi[m][tx * 4];
    float4 n4 = *(const float4*)&bn[m][tx * 4];
    float ar[4] = {a4.x, a4.y, a4.z, a4.w};
    float ir[4] = {i4.x, i4.y, i4.z, i4.w};
    float nr[4] = {n4.x, n4.y, n4.z, n4.w};
    #pragma unroll
    for (int u = 0; u < 4; ++u)
      #pragma unroll
      for (int v = 0; v < 4; ++v) { ai[u][v] += ar[u] * ir[v]; an[u][v] += ar[u] * nr[v]; }
  }
  int kg = k0 + ty * 4;
  if (kg <= 512) {
    #pragma unroll
    for (int v = 0; v < 4; ++v) {
      int fg = f0 + tx * 4 + v;
      if (fg >= FRM) continue;
      float4 vl, vk;
      vl.x = __logf(fmaxf(ai[0][v], 1e-6f)); vl.y = __logf(fmaxf(ai[1][v], 1e-6f));
      vl.z = __logf(fmaxf(ai[2][v], 1e-6f)); vl.w = __logf(fmaxf(ai[3][v], 1e-6f));
      vk.x = fmaxf(an[0][v], 0.0f); vk.y = fmaxf(an[1][v], 0.0f);
      vk.z = fmaxf(an[2][v], 0.0f); vk.w = fmaxf(an[3][v], 0.0f);
      *(float4*)(la + ((size_t)b * FRM + fg) * FBP + kg) = vl;
      *(float4*)(kn + ((size_t)b * FRM + fg) * FBP + kg) = vk;
    }
  }
}

// ============================ in-LDS radix-4 1024-pt FFT, NATURAL in / NATURAL out ============================
__device__ __forceinline__ void fftc(float2* c, const float2* tw, bool inv) {
  int tid = threadIdx.x;  // 256 threads
  __syncthreads();
  {
    int rb = r4(tid);
    float2 a0 = c[PD2(rb)], a1 = c[PD2(rb + 256)], a2 = c[PD2(rb + 512)], a3 = c[PD2(rb + 768)];
    __syncthreads();
    float t0r = a0.x + a2.x, t0i = a0.y + a2.y;
    float t1r = a0.x - a2.x, t1i = a0.y - a2.y;
    float t2r = a1.x + a3.x, t2i = a1.y + a3.y;
    float t3r = a1.x - a3.x, t3i = a1.y - a3.y;
    int base = tid << 2;
    c[PD2(base)]     = make_float2(t0r + t2r, t0i + t2i);
    c[PD2(base + 2)] = make_float2(t0r - t2r, t0i - t2i);
    if (!inv) {
      c[PD2(base + 1)] = make_float2(t1r + t3i, t1i - t3r);
      c[PD2(base + 3)] = make_float2(t1r - t3i, t1i + t3r);
    } else {
      c[PD2(base + 1)] = make_float2(t1r - t3i, t1i + t3r);
      c[PD2(base + 3)] = make_float2(t1r + t3i, t1i - t3r);
    }
    __syncthreads();
  }
  #pragma unroll
  for (int s = 1; s < 5; ++s) {
    int m = 1 << (2 * s);
    int pos = tid & (m - 1);
    int grp = tid >> (2 * s);
    int base = grp * (m << 2) + pos;
    int i0 = PD2(base), i1 = PD2(base + m), i2 = PD2(base + 2 * m), i3 = PD2(base + 3 * m);
    float2 a0 = c[i0], a1 = c[i1], a2 = c[i2], a3 = c[i3];
    {
      int r = 256 >> (2 * s);
      float2 w1 = tw[PD2(pos * r)];
      if (inv) w1.y = -w1.y;
      float2 w2 = cmul(w1, w1);
      float2 w3 = cmul(w2, w1);
      a1 = cmul(a1, w1); a2 = cmul(a2, w2); a3 = cmul(a3, w3);
    }
    float t0r = a0.x + a2.x, t0i = a0.y + a2.y;
    float t1r = a0.x - a2.x, t1i = a0.y - a2.y;
    float t2r = a1.x + a3.x, t2i = a1.y + a3.y;
    float t3r = a1.x - a3.x, t3i = a1.y - a3.y;
    c[i0] = make_float2(t0r + t2r, t0i + t2i);
    c[i2] = make_float2(t0r - t2r, t0i - t2i);
    if (!inv) {
      c[i1] = make_float2(t1r + t3i, t1i - t3r);
      c[i3] = make_float2(t1r - t3i, t1i + t3r);
    } else {
      c[i1] = make_float2(t1r - t3i, t1i + t3r);
      c[i3] = make_float2(t1r + t3i, t1i - t3r);
    }
    __syncthreads();
  }
}

#define LOAD_TWL() do { twl[PD2(tid)] = ((const float2*)twg)[tid]; } while (0)

// ============================ FUSED minphase + STFT filter + paired iSTFT (2 frames/WG) ============================
// Phase M: packed min-phase (la_A + i*la_B) -> kimp_A/B in LDS.
// Phase A/B: STFT(imp + i*noi), filter with kp (LDS) + kn, -> vvA/vvB.
// Final: paired inverse IFFT(V_A + i*V_B) -> 2 windowed frames.
__global__ __launch_bounds__(256) void k_comb3(const float* __restrict__ impc, const float* __restrict__ noise,
                                               const float* __restrict__ hann, const float* __restrict__ invmel,
                                               const float* __restrict__ envimp, const float* __restrict__ envnoi,
                                               float* __restrict__ frames, const float* __restrict__ twg,
                                               const float* __restrict__ lab, const float* __restrict__ knb) {
  int gid = blockIdx.x; int b = gid / 400; int pr = gid % 400;
  int fA = 2 * pr + 1, fB = fA + 1;           // 1-based frame indices
  int r0 = b * FRM + 2 * pr;                  // 0-based row for frame A
  __shared__ float2 c[1088], twl[272], vvA[545], vvB[545], kpA[545], kpB[545];
  __shared__ float envA[80], envB[80], envc[160];
  int tid = threadIdx.x;
  LOAD_TWL();
  if (!knb && tid < 160) {
    int mm = tid >> 1;
    if (tid & 1) envB[mm] = envnoi[((size_t)b * 80 + mm) * FRM + (fB - 1)];
    else         envA[mm] = envnoi[((size_t)b * 80 + mm) * FRM + (fA - 1)];
  }
  if (!lab && tid < 160) {
    int mm = tid >> 1, fr2 = tid & 1;
    envc[tid] = envimp[((size_t)r0 / FRM * 0 + (size_t)b * 80 + mm) * FRM + 2 * pr + fr2];
  }
  __syncthreads();
  // ---- phase M: min-phase spectrum for both frames ----
  if (lab) {
    const float* l1 = lab + (size_t)r0 * FBP;
    const float* l2 = lab + (size_t)(r0 + 1) * FBP;
    for (int f = tid; f < 513; f += 256) {
      float la1 = l1[f], la2 = l2[f];
      c[PD2(f)] = make_float2(la1, la2);
      if (f >= 1 && f <= 511) c[PD2(1024 - f)] = make_float2(la1, la2);
    }
  } else {
    for (int f = tid; f < 513; f += 256) {
      const float4* iv = (const float4*)(invmel + f * 80);
      float d1 = 0.0f, d2 = 0.0f;
      #pragma unroll 5
      for (int q = 0; q < 20; ++q) {
        float4 v = iv[q];
        d1 += v.x * envc[8*q]   + v.y * envc[8*q+2] + v.z * envc[8*q+4] + v.w * envc[8*q+6];
        d2 += v.x * envc[8*q+1] + v.y * envc[8*q+3] + v.z * envc[8*q+5] + v.w * envc[8*q+7];
      }
      float la1 = __logf(fmaxf(d1, 1e-6f));
      float la2 = __logf(fmaxf(d2, 1e-6f));
      c[PD2(f)] = make_float2(la1, la2);
      if (f >= 1 && f <= 511) c[PD2(1024 - f)] = make_float2(la1, la2);
    }
  }
  fftc(c, twl, true);                        // unscaled inverse
  for (int n = tid; n < 1024; n += 256) {
    float sn = ((n == 0 || n == 512) ? 1.0f : (n < 512 ? 2.0f : 0.0f)) * (1.0f / 1024.0f);
    int pn = PD2(n);
    c[pn].x *= sn; c[pn].y *= sn;
  }
  fftc(c, twl, false);                       // forward
  for (int k = tid; k <= 512; k += 256) {
    int km = (1024 - k) & 1023;
    float2 z = c[PD2(k)], mm2 = c[PD2(km)];
    float f1r = 0.5f * (z.x + mm2.x), f1i = 0.5f * (z.y - mm2.y);
    float f2r = 0.5f * (z.y + mm2.y), f2i = 0.5f * (mm2.x - z.x);
    float e1 = __expf(f1r), e2 = __expf(f2r);
    float s1, c1, s2, c2;
    __sincosf(f1i, &s1, &c1);
    __sincosf(f2i, &s2, &c2);
    kpA[PD2(k)] = make_float2(e1 * c1, e1 * s1);
    kpB[PD2(k)] = make_float2(e2 * c2, e2 * s2);
  }
  __syncthreads();                            // kp ready; c free for STFT passes
  // ---- phases A, B: STFT + filter ----
  #pragma unroll
  for (int pass = 0; pass < 2; ++pass) {
    int f = pass ? fB : fA;
    for (int n = tid; n < 1024; n += 256) {
      int ip = f * 256 + n - 512;
      int ridx = ip < 0 ? -ip : (ip >= TT ? 2 * TT - 2 - ip : ip);   // reflect pad
      float wv = hann[n];
      c[PD2(n)] = make_float2(impc[(size_t)b * TT + ridx] * wv,
                              noise[(size_t)b * TT + ridx] * 0.33333f * wv);
    }
    fftc(c, twl, false);
    const float* knrow = knb ? (knb + ((size_t)b * FRM + (f - 1)) * FBP) : nullptr;
    const float* env = pass ? envB : envA;
    float2* vv = pass ? vvB : vvA;
    const float2* kp_ = pass ? kpB : kpA;
    for (int k = tid; k <= 512; k += 256) {
      int km = (1024 - k) & 1023;
      float2 z = c[PD2(k)], mm2 = c[PD2(km)];
      float Ir = 0.5f * (z.x + mm2.x), Ii = 0.5f * (z.y - mm2.y);
      float Nr = 0.5f * (z.y + mm2.y), Ni = 0.5f * (mm2.x - z.x);
      float2 kp = kp_[PD2(k)];
      float kn;
      if (knrow) {
        kn = knrow[k];
      } else {
        const float4* iv = (const float4*)(invmel + k * 80);
        float dot = 0.0f;
        #pragma unroll 5
        for (int q = 0; q < 20; ++q) {
          float4 v = iv[q];
          dot += v.x * env[4*q] + v.y * env[4*q+1] + v.z * env[4*q+2] + v.w * env[4*q+3];
        }
        kn = dot > 0.0f ? dot : 0.0f;
      }
      vv[PD2(k)] = make_float2(Ir * kp.x - Ii * kp.y + Nr * kn,
                               Ir * kp.y + Ii * kp.x + Ni * kn);
    }
    __syncthreads();   // vv complete; safe to overwrite c next pass
  }
  // ---- paired inverse: IFFT(V_A + i*V_B) = frame_A + i*frame_B ----
  for (int n = tid; n < 1024; n += 256) {
    float2 v;
    if (n <= 512) {
      float2 a = vvA[PD2(n)], bb = vvB[PD2(n)];
      v = make_float2(a.x - bb.y, a.y + bb.x);
    } else {
      float2 a = vvA[PD2(1024 - n)], bb = vvB[PD2(1024 - n)];   // conj(a) + i*conj(b)
      v = make_float2(a.x + bb.y, bb.x - a.y);
    }
    c[PD2(n)] = v;
  }
  fftc(c, twl, true);
  float* frA = frames + (size_t)r0 * 1024;
  float* frB = frames + (size_t)(r0 + 1) * 1024;
  for (int n = tid; n < 1024; n += 256) {
    float2 y = c[PD2(n)];
    float hw = (1.0f / 1024.0f) * hann[n];
    frA[n] = y.x * hw;
    frB[n] = y.y * hw;
  }
}

// ============================ overlap-add + window-square normalize + crop ============================
__global__ __launch_bounds__(256) void k_ola(const float* __restrict__ frames, const float* __restrict__ hann,
                                             float* __restrict__ voi) {
  int idx = blockIdx.x * 256 + threadIdx.x;
  int b = idx / TT; int t2 = idx - b * TT;
  int i = t2 + 512;
  int fhi = i >> 8;
  float sum = 0.0f, wsq = 0.0f;
  for (int f = fhi - 3; f <= fhi; ++f) {
    if (f < 0 || f > 800) continue;
    int n = i - (f << 8);
    float wv = hann[n];
    wsq += wv * wv;
    if (f >= 1) sum += frames[((size_t)b * FRM + f - 1) * 1024 + n];
  }
  voi[idx] = sum / (wsq > 1e-11f ? wsq : 1.0f);
}

// ============================ reverb: partition FFTs ============================
__global__ __launch_bounds__(256) void k_hspec(const float* __restrict__ rvb, float* __restrict__ hs,
                                               const float* __restrict__ twg) {
  int gid = blockIdx.x; int b = gid / 16; int p = gid % 16;
  __shared__ float2 c[1088], twl[272];
  int tid = threadIdx.x;
  LOAD_TWL();
  for (int n = tid; n < 1024; n += 256) {
    c[PD2(n)] = make_float2((n < 512) ? rvb[(size_t)b * 8192 + p * 512 + n] : 0.0f, 0.0f);
  }
  fftc(c, twl, false);
  for (int k = tid; k <= 512; k += 256) {
    ((float2*)hs)[(size_t)(b * 16 + p) * FB + k] = c[PD2(k)];
  }
}

// ============================ voi spectra: 2 segments per FFT (real pairing) ============================
__global__ __launch_bounds__(256) void k_xspec2(const float* __restrict__ voi, float* __restrict__ xs,
                                                const float* __restrict__ twg) {
  int gid = blockIdx.x; int b = gid / 200; int mA = 2 * (gid % 200);   // segments mA, mA+1
  __shared__ float2 c[1088], twl[272];
  int tid = threadIdx.x;
  LOAD_TWL();
  const float* vb = voi + (size_t)b * TT;
  for (int n = tid; n < 1024; n += 256) {
    int gA = (mA - 1) * 512 + n;
    int gB = gA + 512;
    float xa = (gA >= 0) ? vb[gA] : 0.0f;
    float xb = vb[gB];
    c[PD2(n)] = make_float2(xa, xb);
  }
  fftc(c, twl, false);
  float2* xsA = (float2*)xs + (size_t)(b * 400 + mA) * FB;
  float2* xsB = (float2*)xs + (size_t)(b * 400 + mA + 1) * FB;
  for (int k = tid; k <= 512; k += 256) {
    int km = (1024 - k) & 1023;
    float2 z = c[PD2(k)], w = c[PD2(km)];
    xsA[k] = make_float2(0.5f * (z.x + w.x), 0.5f * (z.y - w.y));
    xsB[k] = make_float2(0.5f * (z.y + w.y), 0.5f * (w.x - z.x));
  }
}

// ============================ reverb: accumulate + paired inverse (2 segments per WG) ============================
__global__ __launch_bounds__(256) void k_r22(const float* __restrict__ xsp, const float* __restrict__ hsp,
                                             float* __restrict__ out, const float* __restrict__ twg) {
  int gid = blockIdx.x; int b = gid / 200; int mA = 2 * (gid % 200); int mB = mA + 1;
  __shared__ float2 c[1088], twl[272], vvA[545], vvB[545];
  int tid = threadIdx.x;
  LOAD_TWL();
  const float2* X = (const float2*)xsp + (size_t)b * 400 * FB;
  const float2* H = (const float2*)hsp + (size_t)b * 16 * FB;
  for (int k = tid; k <= 512; k += 256) {
    float arA = 0.0f, aiA = 0.0f, arB = 0.0f, aiB = 0.0f;
    #pragma unroll 4
    for (int jj = 0; jj <= 16; ++jj) {      // j = mB - jj; shares X loads between segments
      int j = mB - jj;
      if (j < 0) break;
      float2 xj = X[(size_t)j * FB + k];
      if (jj <= 15) {
        float2 h = H[(size_t)jj * FB + k];
        arB += xj.x * h.x - xj.y * h.y;
        aiB += xj.x * h.y + xj.y * h.x;
      }
      if (jj >= 1) {
        float2 h = H[(size_t)(jj - 1) * FB + k];
        arA += xj.x * h.x - xj.y * h.y;
        aiA += xj.x * h.y + xj.y * h.x;
      }
    }
    vvA[PD2(k)] = make_float2(arA, aiA);
    vvB[PD2(k)] = make_float2(arB, aiB);
  }
  __syncthreads();
  for (int n = tid; n < 1024; n += 256) {
    float2 v;
    if (n <= 512) {
      float2 a = vvA[PD2(n)], bb = vvB[PD2(n)];
      v = make_float2(a.x - bb.y, a.y + bb.x);
    } else {
      float2 a = vvA[PD2(1024 - n)], bb = vvB[PD2(1024 - n)];
      v = make_float2(a.x + bb.y, bb.x - a.y);
    }
    c[PD2(n)] = v;
  }
  fftc(c, twl, true);
  float* oA = out + (size_t)b * TT + mA * 512;
  float* oB = out + (size_t)b * TT + mB * 512;
  for (int n2 = tid; n2 < 512; n2 += 256) {
    float2 y = c[PD2(512 + n2)];
    oA[n2] = y.x * (1.0f / 1024.0f);
    oB[n2] = y.y * (1.0f / 1024.0f);
  }
}

// ============================ launch ============================
extern "C" void kernel_launch(void* const* d_in, const int* in_sizes, int n_in,
                              void* d_out, int out_size, void* d_ws, size_t ws_size,
                              hipStream_t stream) {
  const float* f0   = (const float*)d_in[0];
  const float* envi = (const float*)d_in[1];
  const float* envn = (const float*)d_in[2];
  const float* vc   = (const float*)d_in[3];
  const float* rvb  = (const float*)d_in[4];
  const float* noi  = (const float*)d_in[5];
  const float* hann = (const float*)d_in[6];
  const float* iml  = (const float*)d_in[7];
  float* out = (float*)d_out;
  float* ws  = (float*)d_ws;

  size_t o = 0;
  float* bufX = ws + o; o += (size_t)B_ * TT;              // f0_up -> imp_c
  float* bufS = ws + o; o += (size_t)B_ * TT;              // imp -> voi
  float* bufK = ws + o; o += (size_t)B_ * FRM * FB * 2;    // la (first 26.4MB) + H spectra (after)
  float* bufF = ws + o; o += (size_t)B_ * FRM * 1024;      // frames -> X spectra
  float* bufT = ws + o; o += 600;                          // twiddles (256 float2)
  float* bufKN = ws + o; o += (size_t)B_ * FRM * FBP;      // kernel_noi (guarded)
  bool pre = (o * sizeof(float) <= ws_size);
  float* la = pre ? bufK : nullptr;                        // la in bufK head (kimp's old home)
  float* hs = bufK + (size_t)B_ * FRM * FBP;               // H spectra after la region
  float* kn = pre ? bufKN : nullptr;

  hipLaunchKernelGGL(k_tw,       dim3(1),     dim3(256),  0, stream, bufT);
  hipLaunchKernelGGL(k_f0b,      dim3(800),   dim3(256),  0, stream, f0, bufX, out);    // X + bsum0 (out = pyramid)
  hipLaunchKernelGGL(k_scan_mid, dim3(16),    dim3(256),  0, stream, out);
  hipLaunchKernelGGL(k_incl1,    dim3(800),   dim3(256),  0, stream, out);
  hipLaunchKernelGGL(k_scan_imp, dim3(12800), dim3(256),  0, stream, bufX, out, bufS);  // imp -> bufS
  hipLaunchKernelGGL(k_conv,     dim3(3200),  dim3(256),  0, stream, bufS, vc, bufX);   // imp_c -> bufX
  if (pre)
    hipLaunchKernelGGL(k_dots,   dim3(16 * 9 * 13), dim3(256), 0, stream, iml, envi, envn, la, kn);
  hipLaunchKernelGGL(k_comb3,    dim3(6400),  dim3(256),  0, stream, bufX, noi, hann, iml, envi, envn, bufF, bufT, la, kn);
  hipLaunchKernelGGL(k_ola,      dim3(12800), dim3(256),  0, stream, bufF, hann, bufS);
  hipLaunchKernelGGL(k_hspec,    dim3(256),   dim3(256),  0, stream, rvb, hs, bufT);
  hipLaunchKernelGGL(k_xspec2,   dim3(3200),  dim3(256),  0, stream, bufS, bufF, bufT);
  hipLaunchKernelGGL(k_r22,      dim3(3200),  dim3(256),  0, stream, bufF, hs, out, bufT);
}